// Round 6
// baseline (694.166 us; speedup 1.0000x reference)
//
#include <hip/hip_runtime.h>

#define HIDDEN 32
#define FF 40
#define SEQ_T 512

typedef __attribute__((ext_vector_type(8))) short short8;
typedef __attribute__((ext_vector_type(4))) float float4v;
typedef __attribute__((ext_vector_type(4))) unsigned uint4v;

// ---------------------------------------------------------------------------
// Transposed fused recurrence (R6). With s = sigma(z_hh), h eliminated (R3):
//   Z(t) = S(t-1) @ Acat + u(t)*wu + beta   -> computed as
//   Z^T(t) = Acat^T @ S_ext^T(t-1)          (MFMA: A-op = Acat^T, B-op = S^T)
// Acat^T is 96 x 64: m = output neuron (0..39 hh | 48..87 ho, pads zero),
//   k = 0..39 s-channels, k=40 u-channel, k=41 bias-channel, k>=42 zero.
// C-layout of Z^T: lane l holds Z[row l&15][col mt*16 + 4g + reg]  (g=l>>4).
// Next step's B-operand needs S^T[k][n=l&15] = S[row l&15][k=8g'+j] -- same
// row per lane, only a column regroup: fixed cross-lane ds_bpermute pattern.
// => no LDS storage, no barriers, no bank conflicts, no write->read drain.
// Precision: 3-term split product (trunc-hi + RN-lo bf16), identical to R5.
// ---------------------------------------------------------------------------

__global__ __launch_bounds__(256, 1) void rnn_prep(
    const float* __restrict__ W1hh, const float* __restrict__ b1hh,
    const float* __restrict__ W2hh, const float* __restrict__ b2hh,
    const float* __restrict__ W1ho, const float* __restrict__ b1ho,
    unsigned short* __restrict__ acatT_hi, unsigned short* __restrict__ acatT_lo)
{
    const int idx = blockIdx.x * 256 + threadIdx.x;
    if (idx >= 96 * 64) return;
    const int m = idx >> 6, k = idx & 63;
    const bool hh = m < 48;
    const int col = hh ? m : m - 48;
    float val = 0.f;
    if (col < FF) {
        const float* W1 = hh ? W1hh : W1ho;
        const float* b1 = hh ? b1hh : b1ho;
        if (k < FF) {
            for (int i = 0; i < HIDDEN; ++i)
                val = __builtin_fmaf(W2hh[k * HIDDEN + i], W1[i * FF + col], val);
        } else if (k == 40) {
            val = W1[HIDDEN * FF + col];
        } else if (k == 41) {
            val = b1[col];
            for (int i = 0; i < HIDDEN; ++i)
                val = __builtin_fmaf(b2hh[i], W1[i * FF + col], val);
        }
    }
    const unsigned vb = __builtin_bit_cast(unsigned, val);
    const unsigned short hi = (unsigned short)(vb >> 16);
    const float hif = __builtin_bit_cast(float, (unsigned)hi << 16);
    const float lo = val - hif;
    const unsigned lb = __builtin_bit_cast(unsigned, lo);
    const unsigned short los = (unsigned short)((lb + 0x7FFFu + ((lb >> 16) & 1u)) >> 16);
    acatT_hi[idx] = hi;
    acatT_lo[idx] = los;
}

__device__ __forceinline__ float sigmoid_fast(float x) {
    const float e = __builtin_amdgcn_exp2f(-x * 1.44269504088896341f);
    return __builtin_amdgcn_rcpf(1.0f + e);
}

// pack (trunc-hi bf16, RN-lo bf16) of v into one dword: [hi16 : lo16]
__device__ __forceinline__ unsigned splitpack(float v) {
    const unsigned b = __builtin_bit_cast(unsigned, v);
    const unsigned hif = b & 0xFFFF0000u;
    const float rr = v - __builtin_bit_cast(float, hif);
    unsigned rb = __builtin_bit_cast(unsigned, rr);
    rb = rb + 0x7FFFu + ((rb >> 16) & 1u);
    return __builtin_amdgcn_perm(b, rb, 0x07060302u);   // [b.hi16 : rb.hi16]
}

// pair the hi-halves / lo-halves of two packed dwords into one frag dword
// result = [x.hi16 : y.hi16] (y in low16)
__device__ __forceinline__ unsigned PHI(unsigned x, unsigned y) {
    return __builtin_amdgcn_perm(x, y, 0x07060302u);
}
__device__ __forceinline__ unsigned PLO(unsigned x, unsigned y) {
    return __builtin_amdgcn_perm(x, y, 0x05040100u);
}

__device__ __forceinline__ int bperm(int byteaddr, unsigned v) {
    return __builtin_amdgcn_ds_bpermute(byteaddr, (int)v);
}

// One wave per 16 batch rows. Lane l: r = l&15 (batch row), g = l>>4.
// Fully unrolled step: build B-frags by cross-lane regroup of last step's
// packed sigma values -> 36 MFMA -> sigma -> splitpack -> repeat.
__global__ __launch_bounds__(64, 1) void rnn_main(
    const float* __restrict__ inputs,
    const unsigned short* __restrict__ acatT_hi,
    const unsigned short* __restrict__ acatT_lo,
    const float* __restrict__ W1hh, const float* __restrict__ b1hh,
    const float* __restrict__ W1ho, const float* __restrict__ b1ho,
    const float* __restrict__ W2ho, const float* __restrict__ b2ho,
    float* __restrict__ ys)
{
    const int l = threadIdx.x;
    const int r = l & 15;
    const int g = l >> 4;
    const int R0 = blockIdx.x * 16;
    const size_t rowbase = (size_t)(R0 + r) * SEQ_T;

    // ---- preload A-frags (Acat^T) : 12 hi + 12 lo frags, 96 VGPRs ----
    short8 Ah[6][2], Al[6][2];
#pragma unroll
    for (int mt = 0; mt < 6; ++mt)
#pragma unroll
        for (int ks = 0; ks < 2; ++ks) {
            const int off = (mt * 16 + r) * 64 + ks * 32 + g * 8;
            Ah[mt][ks] = *(const short8*)(acatT_hi + off);
            Al[mt][ks] = *(const short8*)(acatT_lo + off);
        }

    // per-lane W2ho slice for the ho tiles (j = 16mt+4g+reg, 0 for pads)
    float w2o_l[3][4];
#pragma unroll
    for (int mt = 0; mt < 3; ++mt)
#pragma unroll
        for (int reg = 0; reg < 4; ++reg) {
            const int j = 16 * mt + 4 * g + reg;
            w2o_l[mt][reg] = (j < FF) ? W2ho[j] : 0.f;
        }
    const float b2o = b2ho[0];

    const bool is_g0 = (g == 0), is_g1 = (g == 1);
    // bpermute source addresses (bytes): slotA src lane = r + 16*((2g)&3)
    const int addrA = (r + ((g & 1) << 5)) * 4;  // (2g)&3 = 2*(g&1)
    const int addrB = addrA + 64;                // (2g+1)&3 = (2g)&3 + 1
    const int addrC = r * 4;                     // src lane (r, 0)
    const int addrD = addrC + 64;                // src lane (r, 1)

    unsigned pk[3][4];   // packed split sigma: S[row r][col 16mt+4g+reg]

    // ---- step 0: s(0) = sigma(u0*wu_raw + b1_raw), o(0) direct ----
    float u_cur = inputs[rowbase];
    {
        float op = 0.f;
#pragma unroll
        for (int mt = 0; mt < 3; ++mt)
#pragma unroll
            for (int reg = 0; reg < 4; ++reg) {
                const int col = 16 * mt + 4 * g + reg;
                const int cc = col < FF ? col : FF - 1;       // clamp pads
                const float sh = sigmoid_fast(
                    __builtin_fmaf(u_cur, W1hh[HIDDEN * FF + cc], b1hh[cc]));
                pk[mt][reg] = splitpack(sh);
                const float so = sigmoid_fast(
                    __builtin_fmaf(u_cur, W1ho[HIDDEN * FF + cc], b1ho[cc]));
                op = __builtin_fmaf(so, w2o_l[mt][reg], op);
            }
        op += __shfl_xor(op, 16);
        op += __shfl_xor(op, 32);
        if (l < 16) ys[rowbase] = op + b2o;
    }
    float u_nxt = inputs[rowbase + 1];

    for (int t = 1; t < SEQ_T; ++t) {
        u_cur = u_nxt;
        const unsigned upk = splitpack(u_cur);
        u_nxt = inputs[rowbase + (t < SEQ_T - 1 ? t + 1 : SEQ_T - 1)];

        // ---- cross-lane regroup: build B-frags (S_ext^T) ----
        unsigned vA[4], vB[4], vC[4], vD[4];
#pragma unroll
        for (int reg = 0; reg < 4; ++reg) {
            const unsigned a0 = bperm(addrA, pk[0][reg]);
            const unsigned a1 = bperm(addrA, pk[1][reg]);
            vA[reg] = (g < 2) ? a0 : a1;
            const unsigned b0 = bperm(addrB, pk[0][reg]);
            const unsigned b1 = bperm(addrB, pk[1][reg]);
            vB[reg] = (g < 2) ? b0 : b1;
            vC[reg] = bperm(addrC, pk[2][reg]);
            vD[reg] = bperm(addrD, pk[2][reg]);
        }
        uint4v f0h_d, f0l_d, f1h_d, f1l_d;
        f0h_d.x = PHI(vA[1], vA[0]);  f0h_d.y = PHI(vA[3], vA[2]);
        f0h_d.z = PHI(vB[1], vB[0]);  f0h_d.w = PHI(vB[3], vB[2]);
        f0l_d.x = PLO(vA[1], vA[0]);  f0l_d.y = PLO(vA[3], vA[2]);
        f0l_d.z = PLO(vB[1], vB[0]);  f0l_d.w = PLO(vB[3], vB[2]);
        // f1: g0 -> s cols 32..39; g1 -> (u, 1, 0...); g>=2 -> 0
        f1h_d.x = is_g0 ? PHI(vC[1], vC[0]) : (is_g1 ? ((upk >> 16) | 0x3F800000u) : 0u);
        f1h_d.y = is_g0 ? PHI(vC[3], vC[2]) : 0u;
        f1h_d.z = is_g0 ? PHI(vD[1], vD[0]) : 0u;
        f1h_d.w = is_g0 ? PHI(vD[3], vD[2]) : 0u;
        f1l_d.x = is_g0 ? PLO(vC[1], vC[0]) : (is_g1 ? (upk & 0xFFFFu) : 0u);
        f1l_d.y = is_g0 ? PLO(vC[3], vC[2]) : 0u;
        f1l_d.z = is_g0 ? PLO(vD[1], vD[0]) : 0u;
        f1l_d.w = is_g0 ? PLO(vD[3], vD[2]) : 0u;
        const short8 f0h = __builtin_bit_cast(short8, f0h_d);
        const short8 f0l = __builtin_bit_cast(short8, f0l_d);
        const short8 f1h = __builtin_bit_cast(short8, f1h_d);
        const short8 f1l = __builtin_bit_cast(short8, f1l_d);

        // ---- 36 MFMA: Z^T = Ah@Sh + Ah@Sl + Al@Sh over 2 k-halves ----
        float4v acc[6];
#pragma unroll
        for (int mt = 0; mt < 6; ++mt) acc[mt] = (float4v)0.f;
#pragma unroll
        for (int mt = 0; mt < 6; ++mt) {
            acc[mt] = __builtin_amdgcn_mfma_f32_16x16x32_bf16(Ah[mt][0], f0h, acc[mt], 0, 0, 0);
            acc[mt] = __builtin_amdgcn_mfma_f32_16x16x32_bf16(Ah[mt][0], f0l, acc[mt], 0, 0, 0);
            acc[mt] = __builtin_amdgcn_mfma_f32_16x16x32_bf16(Al[mt][0], f0h, acc[mt], 0, 0, 0);
            acc[mt] = __builtin_amdgcn_mfma_f32_16x16x32_bf16(Ah[mt][1], f1h, acc[mt], 0, 0, 0);
            acc[mt] = __builtin_amdgcn_mfma_f32_16x16x32_bf16(Ah[mt][1], f1l, acc[mt], 0, 0, 0);
            acc[mt] = __builtin_amdgcn_mfma_f32_16x16x32_bf16(Al[mt][1], f1h, acc[mt], 0, 0, 0);
        }

        // ---- hh epilogue: sigma + splitpack (stays in registers) ----
#pragma unroll
        for (int mt = 0; mt < 3; ++mt)
#pragma unroll
            for (int reg = 0; reg < 4; ++reg)
                pk[mt][reg] = splitpack(sigmoid_fast(acc[mt][reg]));

        // ---- ho epilogue: o = sigma(zo) . w2o, reduce over 4 g-lanes ----
        float op = 0.f;
#pragma unroll
        for (int mt = 0; mt < 3; ++mt)
#pragma unroll
            for (int reg = 0; reg < 4; ++reg)
                op = __builtin_fmaf(sigmoid_fast(acc[3 + mt][reg]), w2o_l[mt][reg], op);
        op += __shfl_xor(op, 16);
        op += __shfl_xor(op, 32);
        if (l < 16) ys[rowbase + t] = op + b2o;
    }
}

extern "C" void kernel_launch(void* const* d_in, const int* in_sizes, int n_in,
                              void* d_out, int out_size, void* d_ws, size_t ws_size,
                              hipStream_t stream) {
    const float* inputs = (const float*)d_in[0];
    const float* W1hh   = (const float*)d_in[1];
    const float* b1hh   = (const float*)d_in[2];
    const float* W2hh   = (const float*)d_in[3];
    const float* b2hh   = (const float*)d_in[4];
    const float* W1ho   = (const float*)d_in[5];
    const float* b1ho   = (const float*)d_in[6];
    const float* W2ho   = (const float*)d_in[7];
    const float* b2ho   = (const float*)d_in[8];
    float* ys = (float*)d_out;

    unsigned short* acatT_hi = (unsigned short*)d_ws;     // 96*64 ushorts
    unsigned short* acatT_lo = acatT_hi + 96 * 64;

    const int B = in_sizes[0] / SEQ_T;   // 16384

    rnn_prep<<<(96 * 64 + 255) / 256, 256, 0, stream>>>(
        W1hh, b1hh, W2hh, b2hh, W1ho, b1ho, acatT_hi, acatT_lo);

    const int blocks = B / 16;           // 1024 waves, one per 16 rows
    rnn_main<<<blocks, 64, 0, stream>>>(
        inputs, acatT_hi, acatT_lo, W1hh, b1hh, W1ho, b1ho, W2ho, b2ho, ys);
}

// Round 7
// 580.212 us; speedup vs baseline: 1.1964x; 1.1964x over previous
//
#include <hip/hip_runtime.h>

#define HIDDEN 32
#define FF 40
#define SEQ_T 512
#define LP 19   // dword pitch of s_pk neuron rows (bank spread)

typedef __attribute__((ext_vector_type(8))) short short8;
typedef __attribute__((ext_vector_type(4))) float float4v;
typedef __attribute__((ext_vector_type(4))) unsigned uint4v;

// ---------------------------------------------------------------------------
// Transposed fused recurrence (R6) + two-wave hh/ho pipeline (R7).
//   Z^T(t) = Acat^T @ S_ext^T(t-1);  S = sigma(Z_hh);  o = sigma(Z_ho)@W2ho
// Wave0 (critical): hh tiles 0..2 -> s(t) recurrence, bperm regroup in regs,
//   writes packed sigma dwords [hi:lo] to LDS s_pk[t&1][neuron][row].
// Wave1 (shadow, one step behind): ho tiles 3..5, builds B-frags from LDS
//   reads (no bperm), computes o(t), stores. One __syncthreads per step.
// Precision: 3-term split product (trunc-hi + RN-lo bf16) — same as R5/R6.
// ---------------------------------------------------------------------------

__global__ __launch_bounds__(256, 1) void rnn_prep(
    const float* __restrict__ W1hh, const float* __restrict__ b1hh,
    const float* __restrict__ W2hh, const float* __restrict__ b2hh,
    const float* __restrict__ W1ho, const float* __restrict__ b1ho,
    unsigned short* __restrict__ acatT_hi, unsigned short* __restrict__ acatT_lo)
{
    const int idx = blockIdx.x * 256 + threadIdx.x;
    if (idx >= 96 * 64) return;
    const int m = idx >> 6, k = idx & 63;
    const bool hh = m < 48;
    const int col = hh ? m : m - 48;
    float val = 0.f;
    if (col < FF) {
        const float* W1 = hh ? W1hh : W1ho;
        const float* b1 = hh ? b1hh : b1ho;
        if (k < FF) {
            for (int i = 0; i < HIDDEN; ++i)
                val = __builtin_fmaf(W2hh[k * HIDDEN + i], W1[i * FF + col], val);
        } else if (k == 40) {
            val = W1[HIDDEN * FF + col];
        } else if (k == 41) {
            val = b1[col];
            for (int i = 0; i < HIDDEN; ++i)
                val = __builtin_fmaf(b2hh[i], W1[i * FF + col], val);
        }
    }
    const unsigned vb = __builtin_bit_cast(unsigned, val);
    const unsigned short hi = (unsigned short)(vb >> 16);
    const float hif = __builtin_bit_cast(float, (unsigned)hi << 16);
    const float lo = val - hif;
    const unsigned lb = __builtin_bit_cast(unsigned, lo);
    const unsigned short los = (unsigned short)((lb + 0x7FFFu + ((lb >> 16) & 1u)) >> 16);
    acatT_hi[idx] = hi;
    acatT_lo[idx] = los;
}

__device__ __forceinline__ float sigmoid_fast(float x) {
    const float e = __builtin_amdgcn_exp2f(-x * 1.44269504088896341f);
    return __builtin_amdgcn_rcpf(1.0f + e);
}

// pack (trunc-hi bf16, RN-lo bf16) of v into one dword: [hi16 : lo16]
__device__ __forceinline__ unsigned splitpack(float v) {
    const unsigned b = __builtin_bit_cast(unsigned, v);
    const unsigned hif = b & 0xFFFF0000u;
    const float rr = v - __builtin_bit_cast(float, hif);
    unsigned rb = __builtin_bit_cast(unsigned, rr);
    rb = rb + 0x7FFFu + ((rb >> 16) & 1u);
    return __builtin_amdgcn_perm(b, rb, 0x07060302u);
}

__device__ __forceinline__ unsigned PHI(unsigned x, unsigned y) {
    return __builtin_amdgcn_perm(x, y, 0x07060302u);   // [x.hi16 : y.hi16]
}
__device__ __forceinline__ unsigned PLO(unsigned x, unsigned y) {
    return __builtin_amdgcn_perm(x, y, 0x05040100u);   // [x.lo16 : y.lo16]
}
__device__ __forceinline__ int bperm(int byteaddr, unsigned v) {
    return __builtin_amdgcn_ds_bpermute(byteaddr, (int)v);
}

__global__ __launch_bounds__(128, 2) void rnn_main(
    const float* __restrict__ inputs,
    const unsigned short* __restrict__ acatT_hi,
    const unsigned short* __restrict__ acatT_lo,
    const float* __restrict__ W1hh, const float* __restrict__ b1hh,
    const float* __restrict__ W1ho, const float* __restrict__ b1ho,
    const float* __restrict__ W2ho, const float* __restrict__ b2ho,
    float* __restrict__ ys)
{
    __shared__ unsigned s_pk[2][FF][LP];   // 6080 B

    const int tid = threadIdx.x;
    const int wv  = __builtin_amdgcn_readfirstlane(tid >> 6);  // 0=hh, 1=ho
    const int l = tid & 63;
    const int r = l & 15;        // batch row within tile
    const int g = l >> 4;        // quad
    const int R0 = blockIdx.x * 16;
    const size_t rowbase = (size_t)(R0 + r) * SEQ_T;
    const int mtb = wv * 3;      // wave0: Acat^T tiles 0..2, wave1: 3..5

    // ---- A-frags (this wave's 3 m-tiles), hi+lo: 48 VGPRs ----
    short8 Ah[3][2], Al[3][2];
#pragma unroll
    for (int mt = 0; mt < 3; ++mt)
#pragma unroll
        for (int ks = 0; ks < 2; ++ks) {
            const int off = ((mtb + mt) * 16 + r) * 64 + ks * 32 + g * 8;
            Ah[mt][ks] = *(const short8*)(acatT_hi + off);
            Al[mt][ks] = *(const short8*)(acatT_lo + off);
        }

    float w2o_l[3][4];
#pragma unroll
    for (int mt = 0; mt < 3; ++mt)
#pragma unroll
        for (int reg = 0; reg < 4; ++reg) {
            const int j = 16 * mt + 4 * g + reg;
            w2o_l[mt][reg] = (j < FF) ? W2ho[j] : 0.f;
        }
    const float b2o = b2ho[0];

    const bool is_g0 = (g == 0), is_g1 = (g == 1);
    const int addrA = (r + ((g & 1) << 5)) * 4;
    const int addrB = addrA + 64;
    const int addrC = r * 4;
    const int addrD = addrC + 64;

    unsigned pk[3][4];   // wave0 only: packed split sigma state

    // ---- prologue: t = 0 ----
    float u_cur = inputs[rowbase];
    if (wv == 0) {
#pragma unroll
        for (int mt = 0; mt < 3; ++mt)
#pragma unroll
            for (int reg = 0; reg < 4; ++reg) {
                const int n = 16 * mt + 4 * g + reg;
                const int nc = n < FF ? n : FF - 1;
                const float s0 = sigmoid_fast(
                    __builtin_fmaf(u_cur, W1hh[HIDDEN * FF + nc], b1hh[nc]));
                pk[mt][reg] = splitpack(s0);
                if (n < FF) s_pk[0][n][r] = pk[mt][reg];
            }
    } else {
        float op = 0.f;
#pragma unroll
        for (int mt = 0; mt < 3; ++mt)
#pragma unroll
            for (int reg = 0; reg < 4; ++reg) {
                const int n = 16 * mt + 4 * g + reg;
                const int nc = n < FF ? n : FF - 1;
                const float so = sigmoid_fast(
                    __builtin_fmaf(u_cur, W1ho[HIDDEN * FF + nc], b1ho[nc]));
                op = __builtin_fmaf(so, w2o_l[mt][reg], op);
            }
        op += __shfl_xor(op, 16);
        op += __shfl_xor(op, 32);
        if (l < 16) ys[rowbase] = op + b2o;
    }
    __syncthreads();

    float u_nxt = inputs[rowbase + 1];

    for (int t = 1; t < SEQ_T; ++t) {
        const float u_c = u_nxt;                                   // u(t)
        u_nxt = inputs[rowbase + (t < SEQ_T - 1 ? t + 1 : SEQ_T - 1)];
        const unsigned upk = splitpack(u_c);
        const int rb = (t - 1) & 1;
        const int wb = t & 1;

        if (wv == 0) {
            // ---- critical wave: s(t) = sigma(s(t-1)@A + u wu + beta) ----
            unsigned vA[4], vB[4], vC[4], vD[4];
#pragma unroll
            for (int reg = 0; reg < 4; ++reg) {
                const unsigned a0 = bperm(addrA, pk[0][reg]);
                const unsigned a1 = bperm(addrA, pk[1][reg]);
                vA[reg] = (g < 2) ? a0 : a1;
                const unsigned b0 = bperm(addrB, pk[0][reg]);
                const unsigned b1 = bperm(addrB, pk[1][reg]);
                vB[reg] = (g < 2) ? b0 : b1;
                vC[reg] = bperm(addrC, pk[2][reg]);
                vD[reg] = bperm(addrD, pk[2][reg]);
            }
            uint4v f0h_d, f0l_d, f1h_d, f1l_d;
            f0h_d.x = PHI(vA[1], vA[0]);  f0h_d.y = PHI(vA[3], vA[2]);
            f0h_d.z = PHI(vB[1], vB[0]);  f0h_d.w = PHI(vB[3], vB[2]);
            f0l_d.x = PLO(vA[1], vA[0]);  f0l_d.y = PLO(vA[3], vA[2]);
            f0l_d.z = PLO(vB[1], vB[0]);  f0l_d.w = PLO(vB[3], vB[2]);
            f1h_d.x = is_g0 ? PHI(vC[1], vC[0]) : (is_g1 ? ((upk >> 16) | 0x3F800000u) : 0u);
            f1h_d.y = is_g0 ? PHI(vC[3], vC[2]) : 0u;
            f1h_d.z = is_g0 ? PHI(vD[1], vD[0]) : 0u;
            f1h_d.w = is_g0 ? PHI(vD[3], vD[2]) : 0u;
            f1l_d.x = is_g0 ? PLO(vC[1], vC[0]) : (is_g1 ? (upk & 0xFFFFu) : 0u);
            f1l_d.y = is_g0 ? PLO(vC[3], vC[2]) : 0u;
            f1l_d.z = is_g0 ? PLO(vD[1], vD[0]) : 0u;
            f1l_d.w = is_g0 ? PLO(vD[3], vD[2]) : 0u;
            const short8 f0h = __builtin_bit_cast(short8, f0h_d);
            const short8 f0l = __builtin_bit_cast(short8, f0l_d);
            const short8 f1h = __builtin_bit_cast(short8, f1h_d);
            const short8 f1l = __builtin_bit_cast(short8, f1l_d);

            float4v acc[3];
#pragma unroll
            for (int mt = 0; mt < 3; ++mt) acc[mt] = (float4v)0.f;
#pragma unroll
            for (int mt = 0; mt < 3; ++mt) {
                acc[mt] = __builtin_amdgcn_mfma_f32_16x16x32_bf16(Ah[mt][0], f0h, acc[mt], 0, 0, 0);
                acc[mt] = __builtin_amdgcn_mfma_f32_16x16x32_bf16(Ah[mt][0], f0l, acc[mt], 0, 0, 0);
                acc[mt] = __builtin_amdgcn_mfma_f32_16x16x32_bf16(Al[mt][0], f0h, acc[mt], 0, 0, 0);
                acc[mt] = __builtin_amdgcn_mfma_f32_16x16x32_bf16(Ah[mt][1], f1h, acc[mt], 0, 0, 0);
                acc[mt] = __builtin_amdgcn_mfma_f32_16x16x32_bf16(Ah[mt][1], f1l, acc[mt], 0, 0, 0);
                acc[mt] = __builtin_amdgcn_mfma_f32_16x16x32_bf16(Al[mt][1], f1h, acc[mt], 0, 0, 0);
            }
#pragma unroll
            for (int mt = 0; mt < 3; ++mt)
#pragma unroll
                for (int reg = 0; reg < 4; ++reg) {
                    pk[mt][reg] = splitpack(sigmoid_fast(acc[mt][reg]));
                    const int n = 16 * mt + 4 * g + reg;
                    if (n < FF) s_pk[wb][n][r] = pk[mt][reg];
                }
        } else {
            // ---- shadow wave: o(t) from s(t-1) in LDS ----
            unsigned d[8], e[8];
#pragma unroll
            for (int j = 0; j < 8; ++j) d[j] = s_pk[rb][8 * g + j][r];
#pragma unroll
            for (int j = 0; j < 8; ++j) e[j] = s_pk[rb][32 + j][r];
            uint4v f0h_d, f0l_d, f1h_d, f1l_d;
            f0h_d.x = PHI(d[1], d[0]);  f0h_d.y = PHI(d[3], d[2]);
            f0h_d.z = PHI(d[5], d[4]);  f0h_d.w = PHI(d[7], d[6]);
            f0l_d.x = PLO(d[1], d[0]);  f0l_d.y = PLO(d[3], d[2]);
            f0l_d.z = PLO(d[5], d[4]);  f0l_d.w = PLO(d[7], d[6]);
            f1h_d.x = is_g0 ? PHI(e[1], e[0]) : (is_g1 ? ((upk >> 16) | 0x3F800000u) : 0u);
            f1h_d.y = is_g0 ? PHI(e[3], e[2]) : 0u;
            f1h_d.z = is_g0 ? PHI(e[5], e[4]) : 0u;
            f1h_d.w = is_g0 ? PHI(e[7], e[6]) : 0u;
            f1l_d.x = is_g0 ? PLO(e[1], e[0]) : (is_g1 ? (upk & 0xFFFFu) : 0u);
            f1l_d.y = is_g0 ? PLO(e[3], e[2]) : 0u;
            f1l_d.z = is_g0 ? PLO(e[5], e[4]) : 0u;
            f1l_d.w = is_g0 ? PLO(e[7], e[6]) : 0u;
            const short8 f0h = __builtin_bit_cast(short8, f0h_d);
            const short8 f0l = __builtin_bit_cast(short8, f0l_d);
            const short8 f1h = __builtin_bit_cast(short8, f1h_d);
            const short8 f1l = __builtin_bit_cast(short8, f1l_d);

            float4v acc[3];
#pragma unroll
            for (int mt = 0; mt < 3; ++mt) acc[mt] = (float4v)0.f;
#pragma unroll
            for (int mt = 0; mt < 3; ++mt) {
                acc[mt] = __builtin_amdgcn_mfma_f32_16x16x32_bf16(Ah[mt][0], f0h, acc[mt], 0, 0, 0);
                acc[mt] = __builtin_amdgcn_mfma_f32_16x16x32_bf16(Ah[mt][0], f0l, acc[mt], 0, 0, 0);
                acc[mt] = __builtin_amdgcn_mfma_f32_16x16x32_bf16(Al[mt][0], f0h, acc[mt], 0, 0, 0);
                acc[mt] = __builtin_amdgcn_mfma_f32_16x16x32_bf16(Ah[mt][1], f1h, acc[mt], 0, 0, 0);
                acc[mt] = __builtin_amdgcn_mfma_f32_16x16x32_bf16(Ah[mt][1], f1l, acc[mt], 0, 0, 0);
                acc[mt] = __builtin_amdgcn_mfma_f32_16x16x32_bf16(Al[mt][1], f1h, acc[mt], 0, 0, 0);
            }
            float op = 0.f;
#pragma unroll
            for (int mt = 0; mt < 3; ++mt)
#pragma unroll
                for (int reg = 0; reg < 4; ++reg)
                    op = __builtin_fmaf(sigmoid_fast(acc[mt][reg]), w2o_l[mt][reg], op);
            op += __shfl_xor(op, 16);
            op += __shfl_xor(op, 32);
            if (l < 16) ys[rowbase + t] = op + b2o;
        }
        __syncthreads();
    }
}

extern "C" void kernel_launch(void* const* d_in, const int* in_sizes, int n_in,
                              void* d_out, int out_size, void* d_ws, size_t ws_size,
                              hipStream_t stream) {
    const float* inputs = (const float*)d_in[0];
    const float* W1hh   = (const float*)d_in[1];
    const float* b1hh   = (const float*)d_in[2];
    const float* W2hh   = (const float*)d_in[3];
    const float* b2hh   = (const float*)d_in[4];
    const float* W1ho   = (const float*)d_in[5];
    const float* b1ho   = (const float*)d_in[6];
    const float* W2ho   = (const float*)d_in[7];
    const float* b2ho   = (const float*)d_in[8];
    float* ys = (float*)d_out;

    unsigned short* acatT_hi = (unsigned short*)d_ws;     // 96*64 ushorts
    unsigned short* acatT_lo = acatT_hi + 96 * 64;

    const int B = in_sizes[0] / SEQ_T;   // 16384

    rnn_prep<<<(96 * 64 + 255) / 256, 256, 0, stream>>>(
        W1hh, b1hh, W2hh, b2hh, W1ho, b1ho, acatT_hi, acatT_lo);

    const int blocks = B / 16;           // 1024 blocks x 2 waves (hh + ho)
    rnn_main<<<blocks, 128, 0, stream>>>(
        inputs, acatT_hi, acatT_lo, W1hh, b1hh, W1ho, b1ho, W2ho, b2ho, ys);
}

// Round 8
// 539.868 us; speedup vs baseline: 1.2858x; 1.0747x over previous
//
#include <hip/hip_runtime.h>

#define HIDDEN 32
#define FF 40
#define SEQ_T 512
#define RP 18    // ring row pitch (dwords): 4*18*g mod 32 = 8 -> 2-way = free
#define RD 8     // ring depth (slots); producer/consumer distance 2..6 mod 8

typedef __attribute__((ext_vector_type(8))) short short8;
typedef __attribute__((ext_vector_type(4))) float float4v;
typedef __attribute__((ext_vector_type(4))) unsigned uint4v;

// ---------------------------------------------------------------------------
// Transposed fused recurrence (R6) + decoupled hh/ho waves via ring (R8).
//   Z^T(t) = Acat^T @ S_ext^T(t-1);  S = sigma(Z_hh);  o = sigma(Z_ho)@W2ho
// Wave0 (critical): s(t) recurrence, bperm regroup in regs, writes packed
//   sigma dwords to ring[t&7]. Wave1: o(t) three steps behind, reads ring.
// Barrier every 3 steps (172 total) instead of every step (R7's 511).
// Precision: 3-term split product (trunc-hi + RN-lo bf16) — same as R5-R7.
// ---------------------------------------------------------------------------

__global__ __launch_bounds__(256, 1) void rnn_prep(
    const float* __restrict__ W1hh, const float* __restrict__ b1hh,
    const float* __restrict__ W2hh, const float* __restrict__ b2hh,
    const float* __restrict__ W1ho, const float* __restrict__ b1ho,
    unsigned short* __restrict__ acatT_hi, unsigned short* __restrict__ acatT_lo)
{
    const int idx = blockIdx.x * 256 + threadIdx.x;
    if (idx >= 96 * 64) return;
    const int m = idx >> 6, k = idx & 63;
    const bool hh = m < 48;
    const int col = hh ? m : m - 48;
    float val = 0.f;
    if (col < FF) {
        const float* W1 = hh ? W1hh : W1ho;
        const float* b1 = hh ? b1hh : b1ho;
        if (k < FF) {
            for (int i = 0; i < HIDDEN; ++i)
                val = __builtin_fmaf(W2hh[k * HIDDEN + i], W1[i * FF + col], val);
        } else if (k == 40) {
            val = W1[HIDDEN * FF + col];
        } else if (k == 41) {
            val = b1[col];
            for (int i = 0; i < HIDDEN; ++i)
                val = __builtin_fmaf(b2hh[i], W1[i * FF + col], val);
        }
    }
    const unsigned vb = __builtin_bit_cast(unsigned, val);
    const unsigned short hi = (unsigned short)(vb >> 16);
    const float hif = __builtin_bit_cast(float, (unsigned)hi << 16);
    const float lo = val - hif;
    const unsigned lb = __builtin_bit_cast(unsigned, lo);
    const unsigned short los = (unsigned short)((lb + 0x7FFFu + ((lb >> 16) & 1u)) >> 16);
    acatT_hi[idx] = hi;
    acatT_lo[idx] = los;
}

__device__ __forceinline__ float sigmoid_fast(float x) {
    const float e = __builtin_amdgcn_exp2f(-x * 1.44269504088896341f);
    return __builtin_amdgcn_rcpf(1.0f + e);
}

// pack (trunc-hi bf16, RN-lo bf16) of v into one dword: [hi16 : lo16]
__device__ __forceinline__ unsigned splitpack(float v) {
    const unsigned b = __builtin_bit_cast(unsigned, v);
    const unsigned hif = b & 0xFFFF0000u;
    const float rr = v - __builtin_bit_cast(float, hif);
    unsigned rb = __builtin_bit_cast(unsigned, rr);
    rb = rb + 0x7FFFu + ((rb >> 16) & 1u);
    return __builtin_amdgcn_perm(b, rb, 0x07060302u);
}

__device__ __forceinline__ unsigned PHI(unsigned x, unsigned y) {
    return __builtin_amdgcn_perm(x, y, 0x07060302u);   // [x.hi16 : y.hi16]
}
__device__ __forceinline__ unsigned PLO(unsigned x, unsigned y) {
    return __builtin_amdgcn_perm(x, y, 0x05040100u);   // [x.lo16 : y.lo16]
}
__device__ __forceinline__ int bperm(int byteaddr, unsigned v) {
    return __builtin_amdgcn_ds_bpermute(byteaddr, (int)v);
}

__global__ __launch_bounds__(128, 2) void rnn_main(
    const float* __restrict__ inputs,
    const unsigned short* __restrict__ acatT_hi,
    const unsigned short* __restrict__ acatT_lo,
    const float* __restrict__ W1hh, const float* __restrict__ b1hh,
    const float* __restrict__ W1ho, const float* __restrict__ b1ho,
    const float* __restrict__ W2ho, const float* __restrict__ b2ho,
    float* __restrict__ ys)
{
    __shared__ unsigned ring[RD][48][RP];   // 27648 B

    const int tid = threadIdx.x;
    const int wv  = __builtin_amdgcn_readfirstlane(tid >> 6);  // 0=hh, 1=ho
    const int l = tid & 63;
    const int r = l & 15;        // batch row within tile
    const int g = l >> 4;        // quad
    const int R0 = blockIdx.x * 16;
    const size_t rowbase = (size_t)(R0 + r) * SEQ_T;
    const float* __restrict__ in_row = inputs + rowbase;
    const int mtb = wv * 3;      // wave0: tiles 0..2 (hh), wave1: 3..5 (ho)

    // ---- A-frags (this wave's 3 m-tiles), hi+lo ----
    short8 Ah[3][2], Al[3][2];
#pragma unroll
    for (int mt = 0; mt < 3; ++mt)
#pragma unroll
        for (int ks = 0; ks < 2; ++ks) {
            const int off = ((mtb + mt) * 16 + r) * 64 + ks * 32 + g * 8;
            Ah[mt][ks] = *(const short8*)(acatT_hi + off);
            Al[mt][ks] = *(const short8*)(acatT_lo + off);
        }

    float w2o_l[3][4];
#pragma unroll
    for (int mt = 0; mt < 3; ++mt)
#pragma unroll
        for (int reg = 0; reg < 4; ++reg) {
            const int j = 16 * mt + 4 * g + reg;
            w2o_l[mt][reg] = (j < FF) ? W2ho[j] : 0.f;
        }
    const float b2o = b2ho[0];

    const bool is_g0 = (g == 0), is_g1 = (g == 1);
    const int addrA = (r + ((g & 1) << 5)) * 4;
    const int addrB = addrA + 64;
    const int addrC = r * 4;
    const int addrD = addrC + 64;

    unsigned pk[3][4];   // wave0 only: packed split sigma state

    // ---- prologue: t = 0 ----
    float uc[3];
    {
        const float u0 = in_row[0];
        if (wv == 0) {
#pragma unroll
            for (int mt = 0; mt < 3; ++mt)
#pragma unroll
                for (int reg = 0; reg < 4; ++reg) {
                    const int n = 16 * mt + 4 * g + reg;
                    const int nc = n < FF ? n : FF - 1;
                    const float s0 = sigmoid_fast(
                        __builtin_fmaf(u0, W1hh[HIDDEN * FF + nc], b1hh[nc]));
                    pk[mt][reg] = splitpack(s0);
                    ring[0][n][r] = pk[mt][reg];
                }
            uc[0] = in_row[1]; uc[1] = in_row[2]; uc[2] = in_row[3];
        } else {
            float op = 0.f;
#pragma unroll
            for (int mt = 0; mt < 3; ++mt)
#pragma unroll
                for (int reg = 0; reg < 4; ++reg) {
                    const int n = 16 * mt + 4 * g + reg;
                    const int nc = n < FF ? n : FF - 1;
                    const float so = sigmoid_fast(
                        __builtin_fmaf(u0, W1ho[HIDDEN * FF + nc], b1ho[nc]));
                    op = __builtin_fmaf(so, w2o_l[mt][reg], op);
                }
            op += __shfl_xor(op, 16);
            op += __shfl_xor(op, 32);
            if (l < 16) ys[rowbase] = op + b2o;
            uc[0] = uc[1] = uc[2] = 0.f;   // phase 0 does no ho steps
        }
    }
    __syncthreads();

    // ---- phase loop: wave0 runs steps [3p+1..3p+3], wave1 [3p-2..3p] ----
    for (int p = 0; p < 172; ++p) {
        if (wv == 0) {
            const int tb = 3 * p + 1;
            // prefetch next phase's u
            float un[3];
#pragma unroll
            for (int i = 0; i < 3; ++i) {
                int tn = tb + 3 + i; tn = tn < SEQ_T ? tn : SEQ_T - 1;
                un[i] = in_row[tn];
            }
#pragma unroll
            for (int i = 0; i < 3; ++i) {
                const int t = tb + i;
                if (t < SEQ_T) {
                    const unsigned upk = splitpack(uc[i]);
                    // ---- cross-lane regroup -> B-frags ----
                    unsigned vA[4], vB[4], vC[4], vD[4];
#pragma unroll
                    for (int reg = 0; reg < 4; ++reg) {
                        const unsigned a0 = bperm(addrA, pk[0][reg]);
                        const unsigned a1 = bperm(addrA, pk[1][reg]);
                        vA[reg] = (g < 2) ? a0 : a1;
                        const unsigned b0 = bperm(addrB, pk[0][reg]);
                        const unsigned b1 = bperm(addrB, pk[1][reg]);
                        vB[reg] = (g < 2) ? b0 : b1;
                        vC[reg] = bperm(addrC, pk[2][reg]);
                        vD[reg] = bperm(addrD, pk[2][reg]);
                    }
                    uint4v f0h_d, f0l_d, f1h_d, f1l_d;
                    f0h_d.x = PHI(vA[1], vA[0]);  f0h_d.y = PHI(vA[3], vA[2]);
                    f0h_d.z = PHI(vB[1], vB[0]);  f0h_d.w = PHI(vB[3], vB[2]);
                    f0l_d.x = PLO(vA[1], vA[0]);  f0l_d.y = PLO(vA[3], vA[2]);
                    f0l_d.z = PLO(vB[1], vB[0]);  f0l_d.w = PLO(vB[3], vB[2]);
                    f1h_d.x = is_g0 ? PHI(vC[1], vC[0]) : (is_g1 ? ((upk >> 16) | 0x3F800000u) : 0u);
                    f1h_d.y = is_g0 ? PHI(vC[3], vC[2]) : 0u;
                    f1h_d.z = is_g0 ? PHI(vD[1], vD[0]) : 0u;
                    f1h_d.w = is_g0 ? PHI(vD[3], vD[2]) : 0u;
                    f1l_d.x = is_g0 ? PLO(vC[1], vC[0]) : (is_g1 ? (upk & 0xFFFFu) : 0u);
                    f1l_d.y = is_g0 ? PLO(vC[3], vC[2]) : 0u;
                    f1l_d.z = is_g0 ? PLO(vD[1], vD[0]) : 0u;
                    f1l_d.w = is_g0 ? PLO(vD[3], vD[2]) : 0u;
                    const short8 f0h = __builtin_bit_cast(short8, f0h_d);
                    const short8 f0l = __builtin_bit_cast(short8, f0l_d);
                    const short8 f1h = __builtin_bit_cast(short8, f1h_d);
                    const short8 f1l = __builtin_bit_cast(short8, f1l_d);

                    float4v acc[3];
#pragma unroll
                    for (int mt = 0; mt < 3; ++mt) acc[mt] = (float4v)0.f;
#pragma unroll
                    for (int mt = 0; mt < 3; ++mt) {
                        acc[mt] = __builtin_amdgcn_mfma_f32_16x16x32_bf16(Ah[mt][0], f0h, acc[mt], 0, 0, 0);
                        acc[mt] = __builtin_amdgcn_mfma_f32_16x16x32_bf16(Ah[mt][0], f0l, acc[mt], 0, 0, 0);
                        acc[mt] = __builtin_amdgcn_mfma_f32_16x16x32_bf16(Al[mt][0], f0h, acc[mt], 0, 0, 0);
                        acc[mt] = __builtin_amdgcn_mfma_f32_16x16x32_bf16(Ah[mt][1], f1h, acc[mt], 0, 0, 0);
                        acc[mt] = __builtin_amdgcn_mfma_f32_16x16x32_bf16(Ah[mt][1], f1l, acc[mt], 0, 0, 0);
                        acc[mt] = __builtin_amdgcn_mfma_f32_16x16x32_bf16(Al[mt][1], f1h, acc[mt], 0, 0, 0);
                    }
                    const int slot = t & (RD - 1);
#pragma unroll
                    for (int mt = 0; mt < 3; ++mt)
#pragma unroll
                        for (int reg = 0; reg < 4; ++reg) {
                            pk[mt][reg] = splitpack(sigmoid_fast(acc[mt][reg]));
                            ring[slot][16 * mt + 4 * g + reg][r] = pk[mt][reg];
                        }
                }
            }
            uc[0] = un[0]; uc[1] = un[1]; uc[2] = un[2];
        } else {
            const int tb = 3 * p - 2;
            float un[3];
#pragma unroll
            for (int i = 0; i < 3; ++i) {
                int tn = tb + 3 + i; tn = tn < SEQ_T ? tn : SEQ_T - 1;
                if (tn < 1) tn = 1;
                un[i] = in_row[tn];
            }
#pragma unroll
            for (int i = 0; i < 3; ++i) {
                const int t = tb + i;
                if (t >= 1 && t < SEQ_T) {
                    const unsigned upk = splitpack(uc[i]);
                    const int sl = (t - 1) & (RD - 1);
                    unsigned d[8], e[8];
#pragma unroll
                    for (int j = 0; j < 8; ++j) d[j] = ring[sl][8 * g + j][r];
#pragma unroll
                    for (int j = 0; j < 8; ++j) e[j] = ring[sl][32 + j][r];
                    uint4v f0h_d, f0l_d, f1h_d, f1l_d;
                    f0h_d.x = PHI(d[1], d[0]);  f0h_d.y = PHI(d[3], d[2]);
                    f0h_d.z = PHI(d[5], d[4]);  f0h_d.w = PHI(d[7], d[6]);
                    f0l_d.x = PLO(d[1], d[0]);  f0l_d.y = PLO(d[3], d[2]);
                    f0l_d.z = PLO(d[5], d[4]);  f0l_d.w = PLO(d[7], d[6]);
                    f1h_d.x = is_g0 ? PHI(e[1], e[0]) : (is_g1 ? ((upk >> 16) | 0x3F800000u) : 0u);
                    f1h_d.y = is_g0 ? PHI(e[3], e[2]) : 0u;
                    f1h_d.z = is_g0 ? PHI(e[5], e[4]) : 0u;
                    f1h_d.w = is_g0 ? PHI(e[7], e[6]) : 0u;
                    f1l_d.x = is_g0 ? PLO(e[1], e[0]) : (is_g1 ? (upk & 0xFFFFu) : 0u);
                    f1l_d.y = is_g0 ? PLO(e[3], e[2]) : 0u;
                    f1l_d.z = is_g0 ? PLO(e[5], e[4]) : 0u;
                    f1l_d.w = is_g0 ? PLO(e[7], e[6]) : 0u;
                    const short8 f0h = __builtin_bit_cast(short8, f0h_d);
                    const short8 f0l = __builtin_bit_cast(short8, f0l_d);
                    const short8 f1h = __builtin_bit_cast(short8, f1h_d);
                    const short8 f1l = __builtin_bit_cast(short8, f1l_d);

                    float4v acc[3];
#pragma unroll
                    for (int mt = 0; mt < 3; ++mt) acc[mt] = (float4v)0.f;
#pragma unroll
                    for (int mt = 0; mt < 3; ++mt) {
                        acc[mt] = __builtin_amdgcn_mfma_f32_16x16x32_bf16(Ah[mt][0], f0h, acc[mt], 0, 0, 0);
                        acc[mt] = __builtin_amdgcn_mfma_f32_16x16x32_bf16(Ah[mt][0], f0l, acc[mt], 0, 0, 0);
                        acc[mt] = __builtin_amdgcn_mfma_f32_16x16x32_bf16(Al[mt][0], f0h, acc[mt], 0, 0, 0);
                        acc[mt] = __builtin_amdgcn_mfma_f32_16x16x32_bf16(Ah[mt][1], f1h, acc[mt], 0, 0, 0);
                        acc[mt] = __builtin_amdgcn_mfma_f32_16x16x32_bf16(Ah[mt][1], f1l, acc[mt], 0, 0, 0);
                        acc[mt] = __builtin_amdgcn_mfma_f32_16x16x32_bf16(Al[mt][1], f1h, acc[mt], 0, 0, 0);
                    }
                    float op = 0.f;
#pragma unroll
                    for (int mt = 0; mt < 3; ++mt)
#pragma unroll
                        for (int reg = 0; reg < 4; ++reg)
                            op = __builtin_fmaf(sigmoid_fast(acc[mt][reg]), w2o_l[mt][reg], op);
                    op += __shfl_xor(op, 16);
                    op += __shfl_xor(op, 32);
                    if (l < 16) ys[rowbase + t] = op + b2o;
                }
            }
            uc[0] = un[0]; uc[1] = un[1]; uc[2] = un[2];
        }
        __syncthreads();
    }
}

extern "C" void kernel_launch(void* const* d_in, const int* in_sizes, int n_in,
                              void* d_out, int out_size, void* d_ws, size_t ws_size,
                              hipStream_t stream) {
    const float* inputs = (const float*)d_in[0];
    const float* W1hh   = (const float*)d_in[1];
    const float* b1hh   = (const float*)d_in[2];
    const float* W2hh   = (const float*)d_in[3];
    const float* b2hh   = (const float*)d_in[4];
    const float* W1ho   = (const float*)d_in[5];
    const float* b1ho   = (const float*)d_in[6];
    const float* W2ho   = (const float*)d_in[7];
    const float* b2ho   = (const float*)d_in[8];
    float* ys = (float*)d_out;

    unsigned short* acatT_hi = (unsigned short*)d_ws;     // 96*64 ushorts
    unsigned short* acatT_lo = acatT_hi + 96 * 64;

    const int B = in_sizes[0] / SEQ_T;   // 16384

    rnn_prep<<<(96 * 64 + 255) / 256, 256, 0, stream>>>(
        W1hh, b1hh, W2hh, b2hh, W1ho, b1ho, acatT_hi, acatT_lo);

    const int blocks = B / 16;           // 1024 blocks x 2 waves (hh + ho)
    rnn_main<<<blocks, 128, 0, stream>>>(
        inputs, acatT_hi, acatT_lo, W1hh, b1hh, W1ho, b1ho, W2ho, b2ho, ys);
}

// Round 9
// 469.755 us; speedup vs baseline: 1.4777x; 1.1493x over previous
//
#include <hip/hip_runtime.h>

#define HIDDEN 32
#define FF 40
#define SEQ_T 512
#define RD 8     // ring depth; producer/consumer slot distance 2..6 mod 8

typedef __attribute__((ext_vector_type(8))) short short8;
typedef __attribute__((ext_vector_type(4))) float float4v;
typedef __attribute__((ext_vector_type(4))) unsigned uint4v;
typedef __attribute__((ext_vector_type(2))) unsigned uint2v;

// ---------------------------------------------------------------------------
// Transposed fused recurrence (R6) + decoupled waves (R8) + frag-ready ring
// (R9):  Z^T(t) = Acat^T @ S_ext^T(t-1);  S = sigma(Z_hh);  o = sigma(Z_ho)@W2ho
// Ring stores S as two bf16 PLANES (hi, lo), k-contiguous per row:
//   ring[slot][plane][r][72 ushorts]  (144 B rows -> b128 reads conflict-free:
//   span 4(r+g) mod 32 = 8 lanes/span = exactly balanced).
// B-frags = 4 x ds_read_b128 + u/bias register injection. No bperm, no
// regroup perms, no pk state. Writes: 6 x ds_write_b64 of v_perm'd hi/lo
// pairs. Precision: 3-term split (trunc-hi bf16 + rounded-lo bf16), as R5-R8.
// ---------------------------------------------------------------------------

__global__ __launch_bounds__(256, 1) void rnn_prep(
    const float* __restrict__ W1hh, const float* __restrict__ b1hh,
    const float* __restrict__ W2hh, const float* __restrict__ b2hh,
    const float* __restrict__ W1ho, const float* __restrict__ b1ho,
    unsigned short* __restrict__ acatT_hi, unsigned short* __restrict__ acatT_lo)
{
    const int idx = blockIdx.x * 256 + threadIdx.x;
    if (idx >= 96 * 64) return;
    const int m = idx >> 6, k = idx & 63;
    const bool hh = m < 48;
    const int col = hh ? m : m - 48;
    float val = 0.f;
    if (col < FF) {
        const float* W1 = hh ? W1hh : W1ho;
        const float* b1 = hh ? b1hh : b1ho;
        if (k < FF) {
            for (int i = 0; i < HIDDEN; ++i)
                val = __builtin_fmaf(W2hh[k * HIDDEN + i], W1[i * FF + col], val);
        } else if (k == 40) {
            val = W1[HIDDEN * FF + col];
        } else if (k == 41) {
            val = b1[col];
            for (int i = 0; i < HIDDEN; ++i)
                val = __builtin_fmaf(b2hh[i], W1[i * FF + col], val);
        }
    }
    const unsigned vb = __builtin_bit_cast(unsigned, val);
    const unsigned short hi = (unsigned short)(vb >> 16);
    const float hif = __builtin_bit_cast(float, (unsigned)hi << 16);
    const float lo = val - hif;
    const unsigned lb = __builtin_bit_cast(unsigned, lo);
    const unsigned short los = (unsigned short)((lb + 0x7FFFu + ((lb >> 16) & 1u)) >> 16);
    acatT_hi[idx] = hi;
    acatT_lo[idx] = los;
}

__device__ __forceinline__ float sigmoid_fast(float x) {
    const float e = __builtin_amdgcn_exp2f(-x * 1.44269504088896341f);
    return __builtin_amdgcn_rcpf(1.0f + e);
}

// dword [hi16(v) : round-bf16(v - hi)] packer (for u-channel injection)
__device__ __forceinline__ unsigned splitpack(float v) {
    const unsigned b = __builtin_bit_cast(unsigned, v);
    const unsigned hif = b & 0xFFFF0000u;
    const float rr = v - __builtin_bit_cast(float, hif);
    unsigned rb = __builtin_bit_cast(unsigned, rr) + 0x8000u;
    return __builtin_amdgcn_perm(b, rb, 0x07060302u);
}

// [x.hi16 : y.hi16], y.hi16 in the LOW half (= lower ushort address)
__device__ __forceinline__ unsigned PHI(unsigned x, unsigned y) {
    return __builtin_amdgcn_perm(x, y, 0x07060302u);
}

__global__ __launch_bounds__(128, 2) void rnn_main(
    const float* __restrict__ inputs,
    const unsigned short* __restrict__ acatT_hi,
    const unsigned short* __restrict__ acatT_lo,
    const float* __restrict__ W1hh, const float* __restrict__ b1hh,
    const float* __restrict__ W1ho, const float* __restrict__ b1ho,
    const float* __restrict__ W2ho, const float* __restrict__ b2ho,
    float* __restrict__ ys)
{
    __shared__ unsigned short ring[RD][2][16][72];   // 36864 B

    const int tid = threadIdx.x;
    const int wv  = __builtin_amdgcn_readfirstlane(tid >> 6);  // 0=hh, 1=ho
    const int l = tid & 63;
    const int r = l & 15;        // batch row within tile
    const int g = l >> 4;        // quad
    const int R0 = blockIdx.x * 16;
    const size_t rowbase = (size_t)(R0 + r) * SEQ_T;
    const float* __restrict__ in_row = inputs + rowbase;
    const int mtb = wv * 3;      // wave0: tiles 0..2 (hh), wave1: 3..5 (ho)

    // ---- A-frags (this wave's 3 m-tiles), hi+lo ----
    short8 Ah[3][2], Al[3][2];
#pragma unroll
    for (int mt = 0; mt < 3; ++mt)
#pragma unroll
        for (int ks = 0; ks < 2; ++ks) {
            const int off = ((mtb + mt) * 16 + r) * 64 + ks * 32 + g * 8;
            Ah[mt][ks] = *(const short8*)(acatT_hi + off);
            Al[mt][ks] = *(const short8*)(acatT_lo + off);
        }

    float w2o_l[3][4];
#pragma unroll
    for (int mt = 0; mt < 3; ++mt)
#pragma unroll
        for (int reg = 0; reg < 4; ++reg) {
            const int j = 16 * mt + 4 * g + reg;
            w2o_l[mt][reg] = (j < FF) ? W2ho[j] : 0.f;
        }
    const float b2o = b2ho[0];
    const bool is_g0 = (g == 0), is_g1 = (g == 1);

    // build 4 B-frags from ring slot sl (+ u/bias injection)
    auto load_frags = [&](int sl, unsigned upk,
                          short8& f0h, short8& f0l, short8& f1h, short8& f1l) {
        const unsigned short* ph = &ring[sl][0][r][0];
        const unsigned short* pl = &ring[sl][1][r][0];
        f0h = *(const short8*)(ph + g * 8);
        f0l = *(const short8*)(pl + g * 8);
        const uint4v th = *(const uint4v*)(ph + 32);
        const uint4v tl = *(const uint4v*)(pl + 32);
        uint4v zh, zl;
        zh.x = is_g0 ? th.x : (is_g1 ? ((upk >> 16) | 0x3F800000u) : 0u);
        zh.y = is_g0 ? th.y : 0u;
        zh.z = is_g0 ? th.z : 0u;
        zh.w = is_g0 ? th.w : 0u;
        zl.x = is_g0 ? tl.x : (is_g1 ? (upk & 0xFFFFu) : 0u);
        zl.y = is_g0 ? tl.y : 0u;
        zl.z = is_g0 ? tl.z : 0u;
        zl.w = is_g0 ? tl.w : 0u;
        f1h = __builtin_bit_cast(short8, zh);
        f1l = __builtin_bit_cast(short8, zl);
    };

    // sigmoid + split-pack 12 z-values and store planes to ring slot
    auto store_s = [&](int slot, const float4v* z) {
#pragma unroll
        for (int mt = 0; mt < 3; ++mt) {
            unsigned b[4], rl[4];
#pragma unroll
            for (int reg = 0; reg < 4; ++reg) {
                const float s = sigmoid_fast(z[mt][reg]);
                b[reg] = __builtin_bit_cast(unsigned, s);
                const float hif = __builtin_bit_cast(float, b[reg] & 0xFFFF0000u);
                rl[reg] = __builtin_bit_cast(unsigned, s - hif) + 0x8000u;
            }
            uint2v hp, lp;
            hp.x = PHI(b[1], b[0]);   hp.y = PHI(b[3], b[2]);
            lp.x = PHI(rl[1], rl[0]); lp.y = PHI(rl[3], rl[2]);
            *(uint2v*)((unsigned*)&ring[slot][0][r][0] + 8 * mt + 2 * g) = hp;
            *(uint2v*)((unsigned*)&ring[slot][1][r][0] + 8 * mt + 2 * g) = lp;
        }
    };

    auto do_mfma = [&](short8 f0h, short8 f0l, short8 f1h, short8 f1l,
                       float4v* acc) {
#pragma unroll
        for (int mt = 0; mt < 3; ++mt) acc[mt] = (float4v)0.f;
#pragma unroll
        for (int mt = 0; mt < 3; ++mt) {
            acc[mt] = __builtin_amdgcn_mfma_f32_16x16x32_bf16(Ah[mt][0], f0h, acc[mt], 0, 0, 0);
            acc[mt] = __builtin_amdgcn_mfma_f32_16x16x32_bf16(Ah[mt][0], f0l, acc[mt], 0, 0, 0);
            acc[mt] = __builtin_amdgcn_mfma_f32_16x16x32_bf16(Al[mt][0], f0h, acc[mt], 0, 0, 0);
            acc[mt] = __builtin_amdgcn_mfma_f32_16x16x32_bf16(Ah[mt][1], f1h, acc[mt], 0, 0, 0);
            acc[mt] = __builtin_amdgcn_mfma_f32_16x16x32_bf16(Ah[mt][1], f1l, acc[mt], 0, 0, 0);
            acc[mt] = __builtin_amdgcn_mfma_f32_16x16x32_bf16(Al[mt][1], f1h, acc[mt], 0, 0, 0);
        }
    };

    // ---- prologue: t = 0 ----
    float uc[3];
    {
        const float u0 = in_row[0];
        if (wv == 0) {
            float4v z[3];
#pragma unroll
            for (int mt = 0; mt < 3; ++mt)
#pragma unroll
                for (int reg = 0; reg < 4; ++reg) {
                    const int n = 16 * mt + 4 * g + reg;
                    const int nc = n < FF ? n : FF - 1;
                    z[mt][reg] = __builtin_fmaf(u0, W1hh[HIDDEN * FF + nc], b1hh[nc]);
                }
            store_s(0, z);
            uc[0] = in_row[1]; uc[1] = in_row[2]; uc[2] = in_row[3];
        } else {
            float op = 0.f;
#pragma unroll
            for (int mt = 0; mt < 3; ++mt)
#pragma unroll
                for (int reg = 0; reg < 4; ++reg) {
                    const int n = 16 * mt + 4 * g + reg;
                    const int nc = n < FF ? n : FF - 1;
                    const float so = sigmoid_fast(
                        __builtin_fmaf(u0, W1ho[HIDDEN * FF + nc], b1ho[nc]));
                    op = __builtin_fmaf(so, w2o_l[mt][reg], op);
                }
            op += __shfl_xor(op, 16);
            op += __shfl_xor(op, 32);
            if (l < 16) ys[rowbase] = op + b2o;
            uc[0] = uc[1] = uc[2] = 0.f;
        }
    }
    __syncthreads();

    // ---- phase loop: wave0 runs steps [3p+1..3p+3], wave1 [3p-2..3p] ----
    for (int p = 0; p < 172; ++p) {
        if (wv == 0) {
            const int tb = 3 * p + 1;
            float un[3];
#pragma unroll
            for (int i = 0; i < 3; ++i) {
                int tn = tb + 3 + i; tn = tn < SEQ_T ? tn : SEQ_T - 1;
                un[i] = in_row[tn];
            }
#pragma unroll
            for (int i = 0; i < 3; ++i) {
                const int t = tb + i;
                if (t < SEQ_T) {
                    const unsigned upk = splitpack(uc[i]);
                    short8 f0h, f0l, f1h, f1l;
                    load_frags((t - 1) & (RD - 1), upk, f0h, f0l, f1h, f1l);
                    float4v acc[3];
                    do_mfma(f0h, f0l, f1h, f1l, acc);
                    store_s(t & (RD - 1), acc);
                }
            }
            uc[0] = un[0]; uc[1] = un[1]; uc[2] = un[2];
        } else {
            const int tb = 3 * p - 2;
            float un[3];
#pragma unroll
            for (int i = 0; i < 3; ++i) {
                int tn = tb + 3 + i; tn = tn < SEQ_T ? tn : SEQ_T - 1;
                if (tn < 1) tn = 1;
                un[i] = in_row[tn];
            }
#pragma unroll
            for (int i = 0; i < 3; ++i) {
                const int t = tb + i;
                if (t >= 1 && t < SEQ_T) {
                    const unsigned upk = splitpack(uc[i]);
                    short8 f0h, f0l, f1h, f1l;
                    load_frags((t - 1) & (RD - 1), upk, f0h, f0l, f1h, f1l);
                    float4v acc[3];
                    do_mfma(f0h, f0l, f1h, f1l, acc);
                    float op = 0.f;
#pragma unroll
                    for (int mt = 0; mt < 3; ++mt)
#pragma unroll
                        for (int reg = 0; reg < 4; ++reg)
                            op = __builtin_fmaf(sigmoid_fast(acc[mt][reg]),
                                                w2o_l[mt][reg], op);
                    op += __shfl_xor(op, 16);
                    op += __shfl_xor(op, 32);
                    if (l < 16) ys[rowbase + t] = op + b2o;
                }
            }
            uc[0] = un[0]; uc[1] = un[1]; uc[2] = un[2];
        }
        __syncthreads();
    }
}

extern "C" void kernel_launch(void* const* d_in, const int* in_sizes, int n_in,
                              void* d_out, int out_size, void* d_ws, size_t ws_size,
                              hipStream_t stream) {
    const float* inputs = (const float*)d_in[0];
    const float* W1hh   = (const float*)d_in[1];
    const float* b1hh   = (const float*)d_in[2];
    const float* W2hh   = (const float*)d_in[3];
    const float* b2hh   = (const float*)d_in[4];
    const float* W1ho   = (const float*)d_in[5];
    const float* b1ho   = (const float*)d_in[6];
    const float* W2ho   = (const float*)d_in[7];
    const float* b2ho   = (const float*)d_in[8];
    float* ys = (float*)d_out;

    unsigned short* acatT_hi = (unsigned short*)d_ws;     // 96*64 ushorts
    unsigned short* acatT_lo = acatT_hi + 96 * 64;

    const int B = in_sizes[0] / SEQ_T;   // 16384

    rnn_prep<<<(96 * 64 + 255) / 256, 256, 0, stream>>>(
        W1hh, b1hh, W2hh, b2hh, W1ho, b1ho, acatT_hi, acatT_lo);

    const int blocks = B / 16;           // 1024 blocks x 2 waves (hh + ho)
    rnn_main<<<blocks, 128, 0, stream>>>(
        inputs, acatT_hi, acatT_lo, W1hh, b1hh, W1ho, b1ho, W2ho, b2ho, ys);
}